// Round 3
// baseline (242.275 us; speedup 1.0000x reference)
//
#include <hip/hip_runtime.h>

// out[i] = [x2, x3, -(k1*x0 + k2*(x0-x1)), k2*(x0-x1)] per row of x (B,4).
// v4: fill-style streaming structure. The harness's own fillBuffer kernel
// hits 6.7 TB/s at 9% occupancy with long per-thread loops; our one-shot
// 4-rows/thread kernel managed only 2.5-3.9 TB/s. So: 2048 blocks x 256
// threads, 16 rows/thread, software-pipelined batches of 4.
// Cache policy is asymmetric: PLAIN loads (x is read-only and partially
// L3-resident across iterations -> FETCH_SIZE was 64 MiB, half free) +
// NONTEMPORAL stores (out is never re-read; don't evict x from L2/L3).

typedef float f32x4 __attribute__((ext_vector_type(4)));

#define BLOCK 256
#define RPT   16          // rows per thread
#define BATCH 4           // pipelined batch size

__device__ __forceinline__ f32x4 ode(const f32x4 t, const float k1, const float k2) {
    const float d = t.x - t.y;          // q0 - q1
    f32x4 o;
    o.x = t.z;                          // qd0
    o.y = t.w;                          // qd1
    o.z = -(k1 * t.x + k2 * d);         // qdd0
    o.w = k2 * d;                       // qdd1
    return o;
}

__global__ __launch_bounds__(BLOCK) void lagrangian_ode_kernel(
    const f32x4* __restrict__ x,
    const float* __restrict__ k1p,
    const float* __restrict__ k2p,
    f32x4* __restrict__ out,
    int n_rows) {
    const float k1 = k1p[0];
    const float k2 = k2p[0];
    const int chunk = BLOCK * RPT;                       // 4096 rows per block
    const int base  = blockIdx.x * chunk + threadIdx.x;

    if (base + (RPT - 1) * BLOCK < n_rows) {
        // Fast path: full chunk, no bounds checks.
        f32x4 v[BATCH], w[BATCH];
#pragma unroll
        for (int r = 0; r < BATCH; ++r) v[r] = x[base + r * BLOCK];

#pragma unroll
        for (int k = 1; k < RPT / BATCH; ++k) {
            // issue next batch's loads before storing current batch
#pragma unroll
            for (int r = 0; r < BATCH; ++r)
                w[r] = x[base + (k * BATCH + r) * BLOCK];
#pragma unroll
            for (int r = 0; r < BATCH; ++r)
                __builtin_nontemporal_store(ode(v[r], k1, k2),
                                            &out[base + ((k - 1) * BATCH + r) * BLOCK]);
#pragma unroll
            for (int r = 0; r < BATCH; ++r) v[r] = w[r];
        }
#pragma unroll
        for (int r = 0; r < BATCH; ++r)
            __builtin_nontemporal_store(ode(v[r], k1, k2),
                                        &out[base + (RPT - BATCH + r) * BLOCK]);
    } else {
        // Tail path (not taken for B = 8388608, kept for correctness).
#pragma unroll
        for (int j = 0; j < RPT; ++j) {
            const int i = base + j * BLOCK;
            if (i < n_rows) {
                __builtin_nontemporal_store(ode(x[i], k1, k2), &out[i]);
            }
        }
    }
}

extern "C" void kernel_launch(void* const* d_in, const int* in_sizes, int n_in,
                              void* d_out, int out_size, void* d_ws, size_t ws_size,
                              hipStream_t stream) {
    // setup_inputs order: t (1), x (B*4), k1 (1), k2 (1)
    const f32x4* x  = (const f32x4*)d_in[1];
    const float* k1 = (const float*)d_in[2];
    const float* k2 = (const float*)d_in[3];
    f32x4* out = (f32x4*)d_out;

    int n_rows = in_sizes[1] / 4;                        // B = 8388608
    int rows_per_block = BLOCK * RPT;                    // 4096
    int grid = (n_rows + rows_per_block - 1) / rows_per_block;  // 2048
    lagrangian_ode_kernel<<<grid, BLOCK, 0, stream>>>(x, k1, k2, out, n_rows);
}

// Round 4
// 238.142 us; speedup vs baseline: 1.0174x; 1.0174x over previous
//
#include <hip/hip_runtime.h>

// out[i] = [x2, x3, -(k1*x0 + k2*(x0-x1)), k2*(x0-x1)] per row of x (B,4).
// v5: replicate the harness fill kernel's winning shape (6.7 TB/s at 9%
// occupancy in the same capture): SMALL grid (1024 wgs = 262144 threads),
// long grid-stride loop (32 rows/thread), nt loads AND nt stores (the
// measured-best cache policy: v2 nt/nt ~71us vs v3 plain/plain 80.6us).
// 8-deep load batches pipelined against 8-deep store batches to keep the
// bus in long read-bursts and write-bursts.

typedef float f32x4 __attribute__((ext_vector_type(4)));

#define BLOCK 256
#define GRID  1024        // 262144 threads; 8.4M rows -> 32 rows/thread
#define BATCH 8           // loads in flight per thread

__device__ __forceinline__ f32x4 ode(const f32x4 t, const float k1, const float k2) {
    const float d = t.x - t.y;          // q0 - q1
    f32x4 o;
    o.x = t.z;                          // qd0
    o.y = t.w;                          // qd1
    o.z = -(k1 * t.x + k2 * d);         // qdd0
    o.w = k2 * d;                       // qdd1
    return o;
}

__global__ __launch_bounds__(BLOCK) void lagrangian_ode_kernel(
    const f32x4* __restrict__ x,
    const float* __restrict__ k1p,
    const float* __restrict__ k2p,
    f32x4* __restrict__ out,
    int n_rows) {
    const float k1 = k1p[0];
    const float k2 = k2p[0];
    const int T   = GRID * BLOCK;                 // total threads = 262144
    const int tid = blockIdx.x * BLOCK + threadIdx.x;

    // Fast path: full batches of BATCH grid-stride steps.
    // n_full = number of complete (BATCH*T)-row super-steps.
    int i = tid;
    f32x4 v[BATCH], w[BATCH];

    if (i + 31 * T < n_rows) {                    // exact for B = 8388608
        // prologue: first batch of 8 nt loads
#pragma unroll
        for (int r = 0; r < BATCH; ++r)
            v[r] = __builtin_nontemporal_load(&x[i + r * T]);

#pragma unroll
        for (int k = 1; k < 32 / BATCH; ++k) {
            // issue next batch's loads (read burst)
#pragma unroll
            for (int r = 0; r < BATCH; ++r)
                w[r] = __builtin_nontemporal_load(&x[i + (k * BATCH + r) * T]);
            // store previous batch (write burst)
#pragma unroll
            for (int r = 0; r < BATCH; ++r)
                __builtin_nontemporal_store(ode(v[r], k1, k2),
                                            &out[i + ((k - 1) * BATCH + r) * T]);
#pragma unroll
            for (int r = 0; r < BATCH; ++r) v[r] = w[r];
        }
        // epilogue: store last batch
#pragma unroll
        for (int r = 0; r < BATCH; ++r)
            __builtin_nontemporal_store(ode(v[r], k1, k2),
                                        &out[i + (32 - BATCH + r) * T]);
    } else {
        // generic tail (not taken for B = 8388608)
        for (; i < n_rows; i += T) {
            __builtin_nontemporal_store(ode(__builtin_nontemporal_load(&x[i]), k1, k2),
                                        &out[i]);
        }
    }
}

extern "C" void kernel_launch(void* const* d_in, const int* in_sizes, int n_in,
                              void* d_out, int out_size, void* d_ws, size_t ws_size,
                              hipStream_t stream) {
    // setup_inputs order: t (1), x (B*4), k1 (1), k2 (1)
    const f32x4* x  = (const f32x4*)d_in[1];
    const float* k1 = (const float*)d_in[2];
    const float* k2 = (const float*)d_in[3];
    f32x4* out = (f32x4*)d_out;

    int n_rows = in_sizes[1] / 4;                 // B = 8388608
    lagrangian_ode_kernel<<<GRID, BLOCK, 0, stream>>>(x, k1, k2, out, n_rows);
}

// Round 5
// 225.379 us; speedup vs baseline: 1.0750x; 1.0566x over previous
//
#include <hip/hip_runtime.h>

// out[i] = [x2, x3, -(k1*x0 + k2*(x0-x1)), k2*(x0-x1)] per row of x (B,4).
// v6 = v1 restored (measured best: 226.2 us total, ~69 us kernel).
// Session A/B matrix (5 structural variants, kernel us):
//   v1 1row/thr nt/nt ~69 | v2 4-batch nt/nt ~71 | v3 plain/plain 80.6
//   v4 16-row plain/nt 85.5 | v5 grid-stride-32 nt/nt ~81
// Conclusion: per-kernel structure is invariant; the timed graph moves
// 1.342 GB/iter (2x512 MiB poison fills + 256 MiB kernel traffic) and
// v1's 226 us = 5.93 TB/s aggregate = ~94% of the 6.29 TB/s achievable
// copy ceiling. The kernel's low apparent BW is the preceding fill's
// posted-write drain landing in its dispatch window. Simplest wins.

typedef float f32x4 __attribute__((ext_vector_type(4)));

__global__ __launch_bounds__(256) void lagrangian_ode_kernel(
    const f32x4* __restrict__ x,
    const float* __restrict__ k1p,
    const float* __restrict__ k2p,
    f32x4* __restrict__ out,
    int n_rows) {
    int i = blockIdx.x * blockDim.x + threadIdx.x;
    if (i >= n_rows) return;
    const float k1 = k1p[0];
    const float k2 = k2p[0];
    f32x4 v = __builtin_nontemporal_load(&x[i]);
    float d = v.x - v.y;          // q0 - q1
    f32x4 o;
    o.x = v.z;                    // qd0
    o.y = v.w;                    // qd1
    o.z = -(k1 * v.x + k2 * d);   // qdd0 = -(dV/dq0)
    o.w = k2 * d;                 // qdd1 = -(dV/dq1)
    __builtin_nontemporal_store(o, &out[i]);
}

extern "C" void kernel_launch(void* const* d_in, const int* in_sizes, int n_in,
                              void* d_out, int out_size, void* d_ws, size_t ws_size,
                              hipStream_t stream) {
    // setup_inputs order: t (1), x (B*4), k1 (1), k2 (1)
    const f32x4* x  = (const f32x4*)d_in[1];
    const float* k1 = (const float*)d_in[2];
    const float* k2 = (const float*)d_in[3];
    f32x4* out = (f32x4*)d_out;

    int n_rows = in_sizes[1] / 4;   // B = 8388608
    int block = 256;
    int grid = (n_rows + block - 1) / block;
    lagrangian_ode_kernel<<<grid, block, 0, stream>>>(x, k1, k2, out, n_rows);
}